// Round 6
// baseline (479.925 us; speedup 1.0000x reference)
//
#include <hip/hip_runtime.h>

typedef unsigned short u16;
typedef __attribute__((ext_vector_type(8))) __bf16 bf16x8;
typedef __attribute__((ext_vector_type(4))) float f32x4;

#define SEQ 2048
#define DMODEL 2048
#define NHEADS 16
#define DHEAD 128

typedef __attribute__((address_space(1))) void gvoid_t;
typedef __attribute__((address_space(3))) void lvoid_t;

__device__ inline void gload_lds16(const void* g, void* l) {
  __builtin_amdgcn_global_load_lds((gvoid_t*)g, (lvoid_t*)l, 16, 0, 0);
}

__device__ inline u16 f2bf(float f) {
  unsigned u = __float_as_uint(f);
  unsigned r = (u + 0x7fffu + ((u >> 16) & 1u)) >> 16;
  return (u16)r;
}

__global__ __launch_bounds__(256) void cvt_f32_bf16(const float* __restrict__ in,
                                                    u16* __restrict__ out, int n4) {
  int i = blockIdx.x * 256 + threadIdx.x;
  if (i >= n4) return;
  float4 v = reinterpret_cast<const float4*>(in)[i];
  ushort4 o;
  o.x = f2bf(v.x); o.y = f2bf(v.y); o.z = f2bf(v.z); o.w = f2bf(v.w);
  reinterpret_cast<ushort4*>(out)[i] = o;
}

// ---------------- 256x256 GEMM, read-ahead pipelined, constexpr dbuf --------
// MFMA clusters ordered kk-OUTERMOST: 8 independent accumulators between
// dependent reuses of the same acc register (hides MFMA latency at 2 waves/SIMD).
#define GBAR() __builtin_amdgcn_s_barrier()
#define SB0() __builtin_amdgcn_sched_barrier(0)
#define WAITLGKM(N) do { asm volatile("s_waitcnt lgkmcnt(" #N ")" ::: "memory"); } while (0)
#define WAITVM(N) do { asm volatile("s_waitcnt vmcnt(" #N ")" ::: "memory"); } while (0)

template <int MODE>
__global__ __launch_bounds__(512, 1) void gemm256(
    const u16* __restrict__ A, const u16* __restrict__ B,
    const float* __restrict__ bias, int M, int N, int K, int nby,
    u16* __restrict__ qb, u16* __restrict__ kb, u16* __restrict__ vtb,
    float* __restrict__ outf) {
  __shared__ __align__(16) u16 As[2][256 * 64];
  __shared__ __align__(16) u16 Bs[2][256 * 64];
  const int nwg = gridDim.x;
  const int cpx = nwg >> 3;
  const int bid = blockIdx.x;
  const int sw = (bid & 7) * cpx + (bid >> 3);  // bijective: nwg % 8 == 0
  const int bx = sw / nby, by = sw % nby;
  const int m0 = bx * 256, n0 = by * 256;
  const int tid = threadIdx.x, lane = tid & 63, w = tid >> 6;
  const int wm = w >> 2, wn = w & 3;
  const int fr = lane & 15, hi = lane >> 4;
  const int g4 = hi * 4;
  const u16* Abase = A + (size_t)m0 * K;
  const u16* Bbase = B + (size_t)n0 * K;

  f32x4 acc[8][4];
#pragma unroll
  for (int i = 0; i < 8; i++)
#pragma unroll
    for (int j = 0; j < 4; j++) acc[i][j] = f32x4{0.f, 0.f, 0.f, 0.f};

#define STAGE(T, P)                                                              \
  do {                                                                           \
    const int t64 = (T) * 64;                                                    \
    _Pragma("unroll") for (int j = 0; j < 4; j++) {                              \
      const int U = (j * 8 + w) * 64 + lane;                                     \
      const int r_ = U >> 3;                                                     \
      const int us = (lane & 7) ^ (r_ & 7);                                      \
      gload_lds16(Abase + (size_t)r_ * K + t64 + us * 8, &As[P][U * 8]);         \
      gload_lds16(Bbase + (size_t)r_ * K + t64 + us * 8, &Bs[P][U * 8]);         \
    }                                                                            \
  } while (0)

#define LDA(AF, H, P)                                                            \
  do {                                                                           \
    _Pragma("unroll") for (int fi = 0; fi < 4; fi++) {                           \
      const int row = wm * 128 + (H) * 64 + fi * 16 + fr;                        \
      _Pragma("unroll") for (int kk = 0; kk < 2; kk++) {                         \
        const int u = (kk * 4 + hi) ^ (row & 7);                                 \
        AF[fi][kk] = *(const bf16x8*)&As[P][row * 64 + u * 8];                    \
      }                                                                          \
    }                                                                            \
  } while (0)

#define LDB(BF, G, P)                                                            \
  do {                                                                           \
    _Pragma("unroll") for (int fj = 0; fj < 2; fj++) {                           \
      const int row = wn * 64 + (G) * 32 + fj * 16 + fr;                         \
      _Pragma("unroll") for (int kk = 0; kk < 2; kk++) {                         \
        const int u = (kk * 4 + hi) ^ (row & 7);                                 \
        BF[fj][kk] = *(const bf16x8*)&Bs[P][row * 64 + u * 8];                    \
      }                                                                          \
    }                                                                            \
  } while (0)

// kk OUTERMOST: consecutive MFMAs hit 8 distinct acc registers
#define MF(AF, BF, H, G)                                                         \
  do {                                                                           \
    __builtin_amdgcn_s_setprio(1);                                               \
    _Pragma("unroll") for (int kk = 0; kk < 2; kk++)                             \
    _Pragma("unroll") for (int fi = 0; fi < 4; fi++)                             \
    _Pragma("unroll") for (int fj = 0; fj < 2; fj++)                             \
      acc[(H) * 4 + fi][(G) * 2 + fj] = __builtin_amdgcn_mfma_f32_16x16x32_bf16( \
          AF[fi][kk], BF[fj][kk], acc[(H) * 4 + fi][(G) * 2 + fj], 0, 0, 0);     \
    __builtin_amdgcn_s_setprio(0);                                               \
  } while (0)

#define TILE(T, P)                                                               \
  do {                                                                           \
    LDA(a, 0, P); SB0();                                                         \
    LDB(b0, 0, P); SB0();                                                        \
    LDB(b1, 1, P); SB0();                                                        \
    GBAR(); SB0();                                                               \
    WAITLGKM(4); SB0();                                                          \
    MF(a, b0, 0, 0);                                                             \
    WAITLGKM(0); SB0();                                                          \
    MF(a, b1, 0, 1);                                                             \
    LDA(a, 1, P); SB0();                                                         \
    WAITLGKM(0); SB0();                                                          \
    GBAR(); SB0();                                                               \
    if ((T) + 2 < NT) STAGE((T) + 2, P);                                         \
    SB0();                                                                       \
    MF(a, b0, 1, 0);                                                             \
    MF(a, b1, 1, 1);                                                             \
    if ((T) + 2 < NT) { WAITVM(8); }                                             \
    else if ((T) + 1 < NT) { WAITVM(0); }                                        \
    SB0();                                                                       \
    GBAR(); SB0();                                                               \
  } while (0)

  const int NT = K >> 6;  // even (K = 2048 -> 32)
  STAGE(0, 0);
  STAGE(1, 1);
  WAITVM(8); SB0();
  GBAR(); SB0();

  bf16x8 a[4][2], b0[2][2], b1[2][2];
  for (int t = 0; t + 1 < NT; t += 2) {
    TILE(t, 0);
    TILE(t + 1, 1);
  }

  if (MODE == 0) {
    const int which = n0 >> 11;
#pragma unroll
    for (int mi = 0; mi < 8; mi++) {
      const int trow = m0 + wm * 128 + mi * 16 + g4;
      const int b = trow >> 11;
      const int t = trow & 2047;
#pragma unroll
      for (int nj = 0; nj < 4; nj++) {
        const int col = n0 + wn * 64 + nj * 16 + fr;
        const int h = (col >> 7) & 15;
        const int dh = col & 127;
        const float bv = bias[col];
        if (which == 2) {
          ushort4 pk;
          pk.x = f2bf(acc[mi][nj][0] + bv);
          pk.y = f2bf(acc[mi][nj][1] + bv);
          pk.z = f2bf(acc[mi][nj][2] + bv);
          pk.w = f2bf(acc[mi][nj][3] + bv);
          *reinterpret_cast<ushort4*>(vtb + ((size_t)(b * NHEADS + h) * DHEAD + dh) * SEQ + t) = pk;
        } else {
          u16* dst = (which == 0) ? qb : kb;
          const float sc = (which == 0) ? 0.08838834764831845f : 1.0f;
#pragma unroll
          for (int r = 0; r < 4; r++)
            dst[((size_t)(b * NHEADS + h) * SEQ + (t + r)) * DHEAD + dh] =
                f2bf((acc[mi][nj][r] + bv) * sc);
        }
      }
    }
  } else {
#pragma unroll
    for (int mi = 0; mi < 8; mi++) {
      const int row = m0 + wm * 128 + mi * 16 + g4;
#pragma unroll
      for (int nj = 0; nj < 4; nj++) {
        const int col = n0 + wn * 64 + nj * 16 + fr;
        const float bv = bias[col];
#pragma unroll
        for (int r = 0; r < 4; r++) outf[(size_t)(row + r) * N + col] = acc[mi][nj][r] + bv;
      }
    }
  }
#undef STAGE
#undef LDA
#undef LDB
#undef MF
#undef TILE
}

// Flash attention, non-causal. Q pre-scaled. Grid: (SEQ/128, B*H). 4 waves,
// wave owns 32 Q rows x 128 dh. SWAPPED QK^T: s = mfma(K, Q) so lane (fr,hi)
// holds S[q=fr][k=ct*16+hi*4+r] -> softmax stats per-lane (q=fr), in-lane
// reduce + 2 shfl_xor; P written k-contiguous. T13 defer-max. MFMA loops
// kk-outermost for dependency hiding.
__global__ __launch_bounds__(256, 2) void attn_fwd(const u16* __restrict__ Q,
                                                   const u16* __restrict__ Kb,
                                                   const u16* __restrict__ VT,
                                                   u16* __restrict__ O) {
  __shared__ __align__(16) u16 Ks[64 * 128];
  __shared__ __align__(16) u16 Vs[128 * 64];
  __shared__ __align__(16) u16 P_lds[4][32][72];
  const int bh = blockIdx.y;
  const int b = bh >> 4, h = bh & 15;
  const int w = threadIdx.x >> 6;
  const int lane = threadIdx.x & 63;
  const int fr = lane & 15;
  const int hi = lane >> 4;
  const int kr = hi * 8;
  const int g4 = hi * 4;
  const int q0w = blockIdx.x * 128 + w * 32;

  const u16* Qp = Q + (size_t)bh * SEQ * DHEAD;
  const u16* Kp = Kb + (size_t)bh * SEQ * DHEAD;
  const u16* Vp = VT + (size_t)bh * DHEAD * SEQ;

  bf16x8 qf[2][4];
#pragma unroll
  for (int mg = 0; mg < 2; mg++)
#pragma unroll
    for (int kk = 0; kk < 4; kk++)
      qf[mg][kk] = *(const bf16x8*)(Qp + (size_t)(q0w + mg * 16 + fr) * DHEAD + kk * 32 + kr);

  f32x4 oacc[2][8];
#pragma unroll
  for (int mg = 0; mg < 2; mg++)
#pragma unroll
    for (int i = 0; i < 8; i++) oacc[mg][i] = f32x4{0.f, 0.f, 0.f, 0.f};
  float mrun[2] = {-1e30f, -1e30f};  // per-lane stats for q = mg*16 + fr
  float lrun[2] = {0.f, 0.f};

  bf16x8 kreg[4], vreg[4];
#pragma unroll
  for (int i = 0; i < 4; i++) {
    const int u = w * 256 + i * 64 + lane;
    const int rK = u >> 4, c16 = u & 15;
    kreg[i] = *(const bf16x8*)(Kp + (size_t)rK * DHEAD + c16 * 8);
    const int rV = u >> 3, c8 = u & 7;
    vreg[i] = *(const bf16x8*)(Vp + (size_t)rV * SEQ + c8 * 8);
  }

  for (int kv0 = 0; kv0 < SEQ; kv0 += 64) {
    __syncthreads();
#pragma unroll
    for (int i = 0; i < 4; i++) {
      const int u = w * 256 + i * 64 + lane;
      const int rK = u >> 4, c16 = u & 15;
      *(bf16x8*)&Ks[rK * 128 + ((c16 ^ (rK & 7)) * 8)] = kreg[i];
      const int rV = u >> 3, c8 = u & 7;
      *(bf16x8*)&Vs[rV * 64 + ((c8 ^ (rV & 7)) * 8)] = vreg[i];
    }
    __syncthreads();
    if (kv0 + 64 < SEQ) {
      const int kvn = kv0 + 64;
#pragma unroll
      for (int i = 0; i < 4; i++) {
        const int u = w * 256 + i * 64 + lane;
        const int rK = u >> 4, c16 = u & 15;
        kreg[i] = *(const bf16x8*)(Kp + (size_t)(kvn + rK) * DHEAD + c16 * 8);
        const int rV = u >> 3, c8 = u & 7;
        vreg[i] = *(const bf16x8*)(Vp + (size_t)rV * SEQ + kvn + c8 * 8);
      }
    }

    // QK^T (swapped, kk-outer): s[mg][ct][r] = S[q=mg*16+fr][k=ct*16+hi*4+r]
    f32x4 s[2][4];
#pragma unroll
    for (int mg = 0; mg < 2; mg++)
#pragma unroll
      for (int ct = 0; ct < 4; ct++) s[mg][ct] = f32x4{0.f, 0.f, 0.f, 0.f};
    __builtin_amdgcn_s_setprio(1);
#pragma unroll
    for (int kk = 0; kk < 4; kk++) {
#pragma unroll
      for (int ct = 0; ct < 4; ct++) {
        const int row = ct * 16 + fr;
        bf16x8 kf = *(const bf16x8*)&Ks[row * 128 + (((kk * 4 + hi) ^ (row & 7)) * 8)];
        s[0][ct] = __builtin_amdgcn_mfma_f32_16x16x32_bf16(kf, qf[0][kk], s[0][ct], 0, 0, 0);
        s[1][ct] = __builtin_amdgcn_mfma_f32_16x16x32_bf16(kf, qf[1][kk], s[1][ct], 0, 0, 0);
      }
    }
    __builtin_amdgcn_s_setprio(0);

    // per-lane tile max (16 values) + 2 shfl across hi-group
    float pm[2];
#pragma unroll
    for (int mg = 0; mg < 2; mg++) {
      f32x4 mv = s[mg][0];
      mv[0] = fmaxf(mv[0], s[mg][1][0]); mv[1] = fmaxf(mv[1], s[mg][1][1]);
      mv[2] = fmaxf(mv[2], s[mg][1][2]); mv[3] = fmaxf(mv[3], s[mg][1][3]);
      mv[0] = fmaxf(mv[0], s[mg][2][0]); mv[1] = fmaxf(mv[1], s[mg][2][1]);
      mv[2] = fmaxf(mv[2], s[mg][2][2]); mv[3] = fmaxf(mv[3], s[mg][2][3]);
      mv[0] = fmaxf(mv[0], s[mg][3][0]); mv[1] = fmaxf(mv[1], s[mg][3][1]);
      mv[2] = fmaxf(mv[2], s[mg][3][2]); mv[3] = fmaxf(mv[3], s[mg][3][3]);
      float p = fmaxf(fmaxf(mv[0], mv[1]), fmaxf(mv[2], mv[3]));
      p = fmaxf(p, __shfl_xor(p, 16, 64));
      p = fmaxf(p, __shfl_xor(p, 32, 64));
      pm[mg] = p;
    }

    // T13 defer-max: rescale only if some row grew by > 8
    const bool need = (pm[0] - mrun[0] > 8.f) || (pm[1] - mrun[1] > 8.f);
    if (__any(need)) {
#pragma unroll
      for (int mg = 0; mg < 2; mg++) {
        float nm = fmaxf(mrun[mg], pm[mg]);
        float sfv = __expf(mrun[mg] - nm);
        mrun[mg] = nm;
        lrun[mg] *= sfv;
        float fac[4];
#pragma unroll
        for (int r = 0; r < 4; r++) fac[r] = __shfl(sfv, g4 + r, 64);
#pragma unroll
        for (int dt = 0; dt < 8; dt++) {
          oacc[mg][dt][0] *= fac[0]; oacc[mg][dt][1] *= fac[1];
          oacc[mg][dt][2] *= fac[2]; oacc[mg][dt][3] *= fac[3];
        }
      }
    }

    // exp, row-sum (in-lane + 2 shfl), P -> LDS (k-contiguous b64 writes)
#pragma unroll
    for (int mg = 0; mg < 2; mg++) {
#pragma unroll
      for (int ct = 0; ct < 4; ct++)
#pragma unroll
        for (int r = 0; r < 4; r++) s[mg][ct][r] = __expf(s[mg][ct][r] - mrun[mg]);
      f32x4 sv = s[mg][0] + s[mg][1] + s[mg][2] + s[mg][3];
      float su = (sv[0] + sv[1]) + (sv[2] + sv[3]);
      su += __shfl_xor(su, 16, 64);
      su += __shfl_xor(su, 32, 64);
      lrun[mg] += su;
#pragma unroll
      for (int ct = 0; ct < 4; ct++) {
        ushort4 pk;
        pk.x = f2bf(s[mg][ct][0]); pk.y = f2bf(s[mg][ct][1]);
        pk.z = f2bf(s[mg][ct][2]); pk.w = f2bf(s[mg][ct][3]);
        *reinterpret_cast<ushort4*>(&P_lds[w][mg * 16 + fr][ct * 16 + g4]) = pk;
      }
    }

    // PV (kk-outer): A-fragment = P rows q=fr
    bf16x8 pf[2][2];
#pragma unroll
    for (int mg = 0; mg < 2; mg++)
#pragma unroll
      for (int kk = 0; kk < 2; kk++)
        pf[mg][kk] = *(const bf16x8*)&P_lds[w][mg * 16 + fr][kk * 32 + kr];
    __builtin_amdgcn_s_setprio(1);
#pragma unroll
    for (int kk = 0; kk < 2; kk++) {
#pragma unroll
      for (int dt = 0; dt < 8; dt++) {
        const int row = dt * 16 + fr;
        bf16x8 vf = *(const bf16x8*)&Vs[row * 64 + (((kk * 4 + hi) ^ (row & 7)) * 8)];
        oacc[0][dt] = __builtin_amdgcn_mfma_f32_16x16x32_bf16(pf[0][kk], vf, oacc[0][dt], 0, 0, 0);
        oacc[1][dt] = __builtin_amdgcn_mfma_f32_16x16x32_bf16(pf[1][kk], vf, oacc[1][dt], 0, 0, 0);
      }
    }
    __builtin_amdgcn_s_setprio(0);
  }

#pragma unroll
  for (int mg = 0; mg < 2; mg++) {
    float linv = 1.0f / lrun[mg];
    float fac[4];
#pragma unroll
    for (int r = 0; r < 4; r++) fac[r] = __shfl(linv, g4 + r, 64);
#pragma unroll
    for (int r = 0; r < 4; r++) {
      const int t = q0w + mg * 16 + g4 + r;
      u16* op = O + ((size_t)(b * SEQ + t)) * DMODEL + h * DHEAD;
#pragma unroll
      for (int dt = 0; dt < 8; dt++) op[dt * 16 + fr] = f2bf(oacc[mg][dt][r] * fac[r]);
    }
  }
}

extern "C" void kernel_launch(void* const* d_in, const int* in_sizes, int n_in,
                              void* d_out, int out_size, void* d_ws, size_t ws_size,
                              hipStream_t stream) {
  const float* x = (const float*)d_in[0];
  const float* qkv_w = (const float*)d_in[1];
  const float* qkv_b = (const float*)d_in[2];
  const float* out_w = (const float*)d_in[3];
  const float* out_b = (const float*)d_in[4];
  float* out = (float*)d_out;

  char* ws = (char*)d_ws;
  u16* xb = (u16*)ws;
  u16* wqkv = (u16*)(ws + 33554432);
  u16* qb = (u16*)(ws + 33554432 + 25165824);
  u16* kb = qb + (size_t)64 * SEQ * DHEAD;
  u16* vtb = kb + (size_t)64 * SEQ * DHEAD;
  u16* attnb = xb;
  u16* outwb = wqkv;

  cvt_f32_bf16<<<16777216 / 4 / 256, 256, 0, stream>>>(x, xb, 16777216 / 4);
  cvt_f32_bf16<<<12582912 / 4 / 256, 256, 0, stream>>>(qkv_w, wqkv, 12582912 / 4);
  gemm256<0><<<768, 512, 0, stream>>>(xb, wqkv, qkv_b, 8192, 6144, 2048, 24, qb, kb, vtb,
                                      nullptr);
  cvt_f32_bf16<<<4194304 / 4 / 256, 256, 0, stream>>>(out_w, outwb, 4194304 / 4);
  dim3 ga(SEQ / 128, 64);
  attn_fwd<<<ga, 256, 0, stream>>>(qb, kb, vtb, attnb);
  gemm256<1><<<256, 512, 0, stream>>>(attnb, outwb, out_b, 8192, 2048, 2048, 8, nullptr,
                                      nullptr, nullptr, out);
}

// Round 7
// 479.701 us; speedup vs baseline: 1.0005x; 1.0005x over previous
//
#include <hip/hip_runtime.h>

typedef unsigned short u16;
typedef __attribute__((ext_vector_type(8))) __bf16 bf16x8;
typedef __attribute__((ext_vector_type(4))) float f32x4;

#define SEQ 2048
#define DMODEL 2048
#define NHEADS 16
#define DHEAD 128

typedef __attribute__((address_space(1))) void gvoid_t;
typedef __attribute__((address_space(3))) void lvoid_t;

__device__ inline void gload_lds16(const void* g, void* l) {
  __builtin_amdgcn_global_load_lds((gvoid_t*)g, (lvoid_t*)l, 16, 0, 0);
}

__device__ inline u16 f2bf(float f) {
  unsigned u = __float_as_uint(f);
  unsigned r = (u + 0x7fffu + ((u >> 16) & 1u)) >> 16;
  return (u16)r;
}

__global__ __launch_bounds__(256) void cvt_f32_bf16(const float* __restrict__ in,
                                                    u16* __restrict__ out, int n4) {
  int i = blockIdx.x * 256 + threadIdx.x;
  if (i >= n4) return;
  float4 v = reinterpret_cast<const float4*>(in)[i];
  ushort4 o;
  o.x = f2bf(v.x); o.y = f2bf(v.y); o.z = f2bf(v.z); o.w = f2bf(v.w);
  reinterpret_cast<ushort4*>(out)[i] = o;
}

// ------- 256x256 GEMM, m201-style 8-phase fine interleave, constexpr dbuf ----
// Per K-tile: 4 phases {ds_read subtile + quarter-granular gload restage; bar;
// lgkm0; 16 MFMA; bar}. Restage targets only LDS quarters whose last reader
// passed a barrier. vmcnt(8) once per tile (phases 4/8), never 0 mid-loop.
#define GBAR() __builtin_amdgcn_s_barrier()
#define SB0() __builtin_amdgcn_sched_barrier(0)
#define WAITLGKM(N) do { asm volatile("s_waitcnt lgkmcnt(" #N ")" ::: "memory"); } while (0)
#define WAITVM(N) do { asm volatile("s_waitcnt vmcnt(" #N ")" ::: "memory"); } while (0)

template <int MODE>
__global__ __launch_bounds__(512, 1) void gemm256(
    const u16* __restrict__ A, const u16* __restrict__ B,
    const float* __restrict__ bias, int M, int N, int K, int nby,
    u16* __restrict__ qb, u16* __restrict__ kb, u16* __restrict__ vtb,
    float* __restrict__ outf) {
  __shared__ __align__(16) u16 As[2][256 * 64];
  __shared__ __align__(16) u16 Bs[2][256 * 64];
  const int nwg = gridDim.x;
  const int cpx = nwg >> 3;
  const int bid = blockIdx.x;
  const int sw = (bid & 7) * cpx + (bid >> 3);  // bijective: nwg % 8 == 0
  const int bx = sw / nby, by = sw % nby;
  const int m0 = bx * 256, n0 = by * 256;
  const int tid = threadIdx.x, lane = tid & 63, w = tid >> 6;
  const int wm = w >> 2, wn = w & 3;
  const int fr = lane & 15, hi = lane >> 4;
  const int g4 = hi * 4;
  const u16* Abase = A + (size_t)m0 * K;
  const u16* Bbase = B + (size_t)n0 * K;

  f32x4 acc[8][4];
#pragma unroll
  for (int i = 0; i < 8; i++)
#pragma unroll
    for (int j = 0; j < 4; j++) acc[i][j] = f32x4{0.f, 0.f, 0.f, 0.f};

// one gload per thread: stage 64-row quarter J of A (or B) for tile T into buf P
#define STAGE_A1(T, P, J)                                                        \
  do {                                                                           \
    const int U = ((J) * 8 + w) * 64 + lane;                                     \
    const int r_ = U >> 3;                                                       \
    const int us = (lane & 7) ^ (r_ & 7);                                        \
    gload_lds16(Abase + (size_t)r_ * K + (T) * 64 + us * 8, &As[P][U * 8]);      \
  } while (0)
#define STAGE_B1(T, P, J)                                                        \
  do {                                                                           \
    const int U = ((J) * 8 + w) * 64 + lane;                                     \
    const int r_ = U >> 3;                                                       \
    const int us = (lane & 7) ^ (r_ & 7);                                        \
    gload_lds16(Bbase + (size_t)r_ * K + (T) * 64 + us * 8, &Bs[P][U * 8]);      \
  } while (0)

#define LDA(AF, H, P)                                                            \
  do {                                                                           \
    _Pragma("unroll") for (int fi = 0; fi < 4; fi++) {                           \
      const int row = wm * 128 + (H) * 64 + fi * 16 + fr;                        \
      _Pragma("unroll") for (int kk = 0; kk < 2; kk++) {                         \
        const int u = (kk * 4 + hi) ^ (row & 7);                                 \
        AF[fi][kk] = *(const bf16x8*)&As[P][row * 64 + u * 8];                    \
      }                                                                          \
    }                                                                            \
  } while (0)

#define LDB(BF, G, P)                                                            \
  do {                                                                           \
    _Pragma("unroll") for (int fj = 0; fj < 2; fj++) {                           \
      const int row = wn * 64 + (G) * 32 + fj * 16 + fr;                         \
      _Pragma("unroll") for (int kk = 0; kk < 2; kk++) {                         \
        const int u = (kk * 4 + hi) ^ (row & 7);                                 \
        BF[fj][kk] = *(const bf16x8*)&Bs[P][row * 64 + u * 8];                    \
      }                                                                          \
    }                                                                            \
  } while (0)

#define MF(AF, BF, H, G)                                                         \
  do {                                                                           \
    __builtin_amdgcn_s_setprio(1);                                               \
    _Pragma("unroll") for (int kk = 0; kk < 2; kk++)                             \
    _Pragma("unroll") for (int fi = 0; fi < 4; fi++)                             \
    _Pragma("unroll") for (int fj = 0; fj < 2; fj++)                             \
      acc[(H) * 4 + fi][(G) * 2 + fj] = __builtin_amdgcn_mfma_f32_16x16x32_bf16( \
          AF[fi][kk], BF[fj][kk], acc[(H) * 4 + fi][(G) * 2 + fj], 0, 0, 0);     \
    __builtin_amdgcn_s_setprio(0);                                               \
  } while (0)

// 4 phases per K-tile. Restage safety: A-H0 quarters (Q0,Q2) last read by ph1's
// LDA -> restage in ph2; B lower half (Q0,Q1) last read by ph2's LDB(b1) ->
// restage in ph3; A-H1 (Q1,Q3) last read ph3, B upper half last read ph2 ->
// restage in ph4. Next-iter reads guarded by vmcnt(8)+barrier at phase 4/8.
#define TILE(T, P)                                                               \
  do {                                                                           \
    /* ph1 */                                                                    \
    LDA(a, 0, P); LDB(b0, 0, P); SB0();                                          \
    GBAR(); WAITLGKM(0); SB0();                                                  \
    MF(a, b0, 0, 0);                                                             \
    GBAR();                                                                      \
    /* ph2 */                                                                    \
    LDB(b1, 1, P); SB0();                                                        \
    if ((T) + 2 < NT) { STAGE_A1((T) + 2, P, 0); STAGE_A1((T) + 2, P, 2); }      \
    SB0();                                                                       \
    GBAR(); WAITLGKM(0); SB0();                                                  \
    MF(a, b1, 0, 1);                                                             \
    GBAR();                                                                      \
    /* ph3 */                                                                    \
    LDA(a, 1, P); SB0();                                                         \
    if ((T) + 2 < NT) { STAGE_B1((T) + 2, P, 0); STAGE_B1((T) + 2, P, 1); }      \
    SB0();                                                                       \
    GBAR(); WAITLGKM(0); SB0();                                                  \
    MF(a, b0, 1, 0);                                                             \
    GBAR();                                                                      \
    /* ph4 */                                                                    \
    if ((T) + 2 < NT) {                                                          \
      STAGE_A1((T) + 2, P, 1); STAGE_A1((T) + 2, P, 3);                          \
      STAGE_B1((T) + 2, P, 2); STAGE_B1((T) + 2, P, 3);                          \
    }                                                                            \
    SB0();                                                                       \
    MF(a, b1, 1, 1);                                                             \
    if ((T) + 2 < NT) { WAITVM(8); }                                             \
    else if ((T) + 1 < NT) { WAITVM(0); }                                        \
    SB0();                                                                       \
    GBAR();                                                                      \
  } while (0)

  const int NT = K >> 6;  // K = 2048 -> 32 (even)
  // prologue: full tiles 0 -> buf0, 1 -> buf1
#pragma unroll
  for (int j = 0; j < 4; j++) { STAGE_A1(0, 0, j); STAGE_B1(0, 0, j); }
#pragma unroll
  for (int j = 0; j < 4; j++) { STAGE_A1(1, 1, j); STAGE_B1(1, 1, j); }
  WAITVM(8); SB0();
  GBAR(); SB0();

  bf16x8 a[4][2], b0[2][2], b1[2][2];
  for (int t = 0; t + 1 < NT; t += 2) {
    TILE(t, 0);
    TILE(t + 1, 1);
  }

  if (MODE == 0) {
    const int which = n0 >> 11;
#pragma unroll
    for (int mi = 0; mi < 8; mi++) {
      const int trow = m0 + wm * 128 + mi * 16 + g4;
      const int b = trow >> 11;
      const int t = trow & 2047;
#pragma unroll
      for (int nj = 0; nj < 4; nj++) {
        const int col = n0 + wn * 64 + nj * 16 + fr;
        const int h = (col >> 7) & 15;
        const int dh = col & 127;
        const float bv = bias[col];
        if (which == 2) {
          ushort4 pk;
          pk.x = f2bf(acc[mi][nj][0] + bv);
          pk.y = f2bf(acc[mi][nj][1] + bv);
          pk.z = f2bf(acc[mi][nj][2] + bv);
          pk.w = f2bf(acc[mi][nj][3] + bv);
          *reinterpret_cast<ushort4*>(vtb + ((size_t)(b * NHEADS + h) * DHEAD + dh) * SEQ + t) = pk;
        } else {
          u16* dst = (which == 0) ? qb : kb;
          const float sc = (which == 0) ? 0.08838834764831845f : 1.0f;
#pragma unroll
          for (int r = 0; r < 4; r++)
            dst[((size_t)(b * NHEADS + h) * SEQ + (t + r)) * DHEAD + dh] =
                f2bf((acc[mi][nj][r] + bv) * sc);
        }
      }
    }
  } else {
#pragma unroll
    for (int mi = 0; mi < 8; mi++) {
      const int row = m0 + wm * 128 + mi * 16 + g4;
#pragma unroll
      for (int nj = 0; nj < 4; nj++) {
        const int col = n0 + wn * 64 + nj * 16 + fr;
        const float bv = bias[col];
#pragma unroll
        for (int r = 0; r < 4; r++) outf[(size_t)(row + r) * N + col] = acc[mi][nj][r] + bv;
      }
    }
  }
#undef STAGE_A1
#undef STAGE_B1
#undef LDA
#undef LDB
#undef MF
#undef TILE
}

// Flash attention, non-causal. Q pre-scaled. Grid: (SEQ/128, B*H). 4 waves,
// wave owns 32 Q rows x 128 dh. SWAPPED QK^T: s = mfma(K, Q) so lane (fr,hi)
// holds S[q=fr][k=ct*16+hi*4+r] -> softmax stats per-lane (q=fr), in-lane
// reduce + 2 shfl_xor; P written k-contiguous. T13 defer-max.
__global__ __launch_bounds__(256, 2) void attn_fwd(const u16* __restrict__ Q,
                                                   const u16* __restrict__ Kb,
                                                   const u16* __restrict__ VT,
                                                   u16* __restrict__ O) {
  __shared__ __align__(16) u16 Ks[64 * 128];
  __shared__ __align__(16) u16 Vs[128 * 64];
  __shared__ __align__(16) u16 P_lds[4][32][72];
  const int bh = blockIdx.y;
  const int b = bh >> 4, h = bh & 15;
  const int w = threadIdx.x >> 6;
  const int lane = threadIdx.x & 63;
  const int fr = lane & 15;
  const int hi = lane >> 4;
  const int kr = hi * 8;
  const int g4 = hi * 4;
  const int q0w = blockIdx.x * 128 + w * 32;

  const u16* Qp = Q + (size_t)bh * SEQ * DHEAD;
  const u16* Kp = Kb + (size_t)bh * SEQ * DHEAD;
  const u16* Vp = VT + (size_t)bh * DHEAD * SEQ;

  bf16x8 qf[2][4];
#pragma unroll
  for (int mg = 0; mg < 2; mg++)
#pragma unroll
    for (int kk = 0; kk < 4; kk++)
      qf[mg][kk] = *(const bf16x8*)(Qp + (size_t)(q0w + mg * 16 + fr) * DHEAD + kk * 32 + kr);

  f32x4 oacc[2][8];
#pragma unroll
  for (int mg = 0; mg < 2; mg++)
#pragma unroll
    for (int i = 0; i < 8; i++) oacc[mg][i] = f32x4{0.f, 0.f, 0.f, 0.f};
  float mrun[2] = {-1e30f, -1e30f};  // per-lane stats for q = mg*16 + fr
  float lrun[2] = {0.f, 0.f};

  bf16x8 kreg[4], vreg[4];
#pragma unroll
  for (int i = 0; i < 4; i++) {
    const int u = w * 256 + i * 64 + lane;
    const int rK = u >> 4, c16 = u & 15;
    kreg[i] = *(const bf16x8*)(Kp + (size_t)rK * DHEAD + c16 * 8);
    const int rV = u >> 3, c8 = u & 7;
    vreg[i] = *(const bf16x8*)(Vp + (size_t)rV * SEQ + c8 * 8);
  }

  for (int kv0 = 0; kv0 < SEQ; kv0 += 64) {
    __syncthreads();
#pragma unroll
    for (int i = 0; i < 4; i++) {
      const int u = w * 256 + i * 64 + lane;
      const int rK = u >> 4, c16 = u & 15;
      *(bf16x8*)&Ks[rK * 128 + ((c16 ^ (rK & 7)) * 8)] = kreg[i];
      const int rV = u >> 3, c8 = u & 7;
      *(bf16x8*)&Vs[rV * 64 + ((c8 ^ (rV & 7)) * 8)] = vreg[i];
    }
    __syncthreads();
    if (kv0 + 64 < SEQ) {
      const int kvn = kv0 + 64;
#pragma unroll
      for (int i = 0; i < 4; i++) {
        const int u = w * 256 + i * 64 + lane;
        const int rK = u >> 4, c16 = u & 15;
        kreg[i] = *(const bf16x8*)(Kp + (size_t)(kvn + rK) * DHEAD + c16 * 8);
        const int rV = u >> 3, c8 = u & 7;
        vreg[i] = *(const bf16x8*)(Vp + (size_t)rV * SEQ + kvn + c8 * 8);
      }
    }

    // QK^T (swapped, kk-outer): s[mg][ct][r] = S[q=mg*16+fr][k=ct*16+hi*4+r]
    f32x4 s[2][4];
#pragma unroll
    for (int mg = 0; mg < 2; mg++)
#pragma unroll
      for (int ct = 0; ct < 4; ct++) s[mg][ct] = f32x4{0.f, 0.f, 0.f, 0.f};
    __builtin_amdgcn_s_setprio(1);
#pragma unroll
    for (int kk = 0; kk < 4; kk++) {
#pragma unroll
      for (int ct = 0; ct < 4; ct++) {
        const int row = ct * 16 + fr;
        bf16x8 kf = *(const bf16x8*)&Ks[row * 128 + (((kk * 4 + hi) ^ (row & 7)) * 8)];
        s[0][ct] = __builtin_amdgcn_mfma_f32_16x16x32_bf16(kf, qf[0][kk], s[0][ct], 0, 0, 0);
        s[1][ct] = __builtin_amdgcn_mfma_f32_16x16x32_bf16(kf, qf[1][kk], s[1][ct], 0, 0, 0);
      }
    }
    __builtin_amdgcn_s_setprio(0);

    // per-lane tile max (16 values) + 2 shfl across hi-group
    float pm[2];
#pragma unroll
    for (int mg = 0; mg < 2; mg++) {
      f32x4 mv = s[mg][0];
      mv[0] = fmaxf(mv[0], s[mg][1][0]); mv[1] = fmaxf(mv[1], s[mg][1][1]);
      mv[2] = fmaxf(mv[2], s[mg][1][2]); mv[3] = fmaxf(mv[3], s[mg][1][3]);
      mv[0] = fmaxf(mv[0], s[mg][2][0]); mv[1] = fmaxf(mv[1], s[mg][2][1]);
      mv[2] = fmaxf(mv[2], s[mg][2][2]); mv[3] = fmaxf(mv[3], s[mg][2][3]);
      mv[0] = fmaxf(mv[0], s[mg][3][0]); mv[1] = fmaxf(mv[1], s[mg][3][1]);
      mv[2] = fmaxf(mv[2], s[mg][3][2]); mv[3] = fmaxf(mv[3], s[mg][3][3]);
      float p = fmaxf(fmaxf(mv[0], mv[1]), fmaxf(mv[2], mv[3]));
      p = fmaxf(p, __shfl_xor(p, 16, 64));
      p = fmaxf(p, __shfl_xor(p, 32, 64));
      pm[mg] = p;
    }

    // T13 defer-max: rescale only if some row grew by > 8
    const bool need = (pm[0] - mrun[0] > 8.f) || (pm[1] - mrun[1] > 8.f);
    if (__any(need)) {
#pragma unroll
      for (int mg = 0; mg < 2; mg++) {
        float nm = fmaxf(mrun[mg], pm[mg]);
        float sfv = __expf(mrun[mg] - nm);
        mrun[mg] = nm;
        lrun[mg] *= sfv;
        float fac[4];
#pragma unroll
        for (int r = 0; r < 4; r++) fac[r] = __shfl(sfv, g4 + r, 64);
#pragma unroll
        for (int dt = 0; dt < 8; dt++) {
          oacc[mg][dt][0] *= fac[0]; oacc[mg][dt][1] *= fac[1];
          oacc[mg][dt][2] *= fac[2]; oacc[mg][dt][3] *= fac[3];
        }
      }
    }

    // exp, row-sum (in-lane + 2 shfl), P -> LDS (k-contiguous b64 writes)
#pragma unroll
    for (int mg = 0; mg < 2; mg++) {
#pragma unroll
      for (int ct = 0; ct < 4; ct++)
#pragma unroll
        for (int r = 0; r < 4; r++) s[mg][ct][r] = __expf(s[mg][ct][r] - mrun[mg]);
      f32x4 sv = s[mg][0] + s[mg][1] + s[mg][2] + s[mg][3];
      float su = (sv[0] + sv[1]) + (sv[2] + sv[3]);
      su += __shfl_xor(su, 16, 64);
      su += __shfl_xor(su, 32, 64);
      lrun[mg] += su;
#pragma unroll
      for (int ct = 0; ct < 4; ct++) {
        ushort4 pk;
        pk.x = f2bf(s[mg][ct][0]); pk.y = f2bf(s[mg][ct][1]);
        pk.z = f2bf(s[mg][ct][2]); pk.w = f2bf(s[mg][ct][3]);
        *reinterpret_cast<ushort4*>(&P_lds[w][mg * 16 + fr][ct * 16 + g4]) = pk;
      }
    }

    // PV (kk-outer): A-fragment = P rows q=fr
    bf16x8 pf[2][2];
#pragma unroll
    for (int mg = 0; mg < 2; mg++)
#pragma unroll
      for (int kk = 0; kk < 2; kk++)
        pf[mg][kk] = *(const bf16x8*)&P_lds[w][mg * 16 + fr][kk * 32 + kr];
    __builtin_amdgcn_s_setprio(1);
#pragma unroll
    for (int kk = 0; kk < 2; kk++) {
#pragma unroll
      for (int dt = 0; dt < 8; dt++) {
        const int row = dt * 16 + fr;
        bf16x8 vf = *(const bf16x8*)&Vs[row * 64 + (((kk * 4 + hi) ^ (row & 7)) * 8)];
        oacc[0][dt] = __builtin_amdgcn_mfma_f32_16x16x32_bf16(pf[0][kk], vf, oacc[0][dt], 0, 0, 0);
        oacc[1][dt] = __builtin_amdgcn_mfma_f32_16x16x32_bf16(pf[1][kk], vf, oacc[1][dt], 0, 0, 0);
      }
    }
    __builtin_amdgcn_s_setprio(0);
  }

#pragma unroll
  for (int mg = 0; mg < 2; mg++) {
    float linv = 1.0f / lrun[mg];
    float fac[4];
#pragma unroll
    for (int r = 0; r < 4; r++) fac[r] = __shfl(linv, g4 + r, 64);
#pragma unroll
    for (int r = 0; r < 4; r++) {
      const int t = q0w + mg * 16 + g4 + r;
      u16* op = O + ((size_t)(b * SEQ + t)) * DMODEL + h * DHEAD;
#pragma unroll
      for (int dt = 0; dt < 8; dt++) op[dt * 16 + fr] = f2bf(oacc[mg][dt][r] * fac[r]);
    }
  }
}

extern "C" void kernel_launch(void* const* d_in, const int* in_sizes, int n_in,
                              void* d_out, int out_size, void* d_ws, size_t ws_size,
                              hipStream_t stream) {
  const float* x = (const float*)d_in[0];
  const float* qkv_w = (const float*)d_in[1];
  const float* qkv_b = (const float*)d_in[2];
  const float* out_w = (const float*)d_in[3];
  const float* out_b = (const float*)d_in[4];
  float* out = (float*)d_out;

  char* ws = (char*)d_ws;
  u16* xb = (u16*)ws;
  u16* wqkv = (u16*)(ws + 33554432);
  u16* qb = (u16*)(ws + 33554432 + 25165824);
  u16* kb = qb + (size_t)64 * SEQ * DHEAD;
  u16* vtb = kb + (size_t)64 * SEQ * DHEAD;
  u16* attnb = xb;
  u16* outwb = wqkv;

  cvt_f32_bf16<<<16777216 / 4 / 256, 256, 0, stream>>>(x, xb, 16777216 / 4);
  cvt_f32_bf16<<<12582912 / 4 / 256, 256, 0, stream>>>(qkv_w, wqkv, 12582912 / 4);
  gemm256<0><<<768, 512, 0, stream>>>(xb, wqkv, qkv_b, 8192, 6144, 2048, 24, qb, kb, vtb,
                                      nullptr);
  cvt_f32_bf16<<<4194304 / 4 / 256, 256, 0, stream>>>(out_w, outwb, 4194304 / 4);
  dim3 ga(SEQ / 128, 64);
  attn_fwd<<<ga, 256, 0, stream>>>(qb, kb, vtb, attnb);
  gemm256<1><<<256, 512, 0, stream>>>(attnb, outwb, out_b, 8192, 2048, 2048, 8, nullptr,
                                      nullptr, nullptr, out);
}